// Round 7
// baseline (155.741 us; speedup 1.0000x reference)
//
#include <hip/hip_runtime.h>
#include <math.h>

// Problem constants (fixed by the reference).
#define M_PTS 16384
#define N_PTS 16384
#define NB 256                    // co-resident blocks (<= 1 per CU guaranteed)
#define NT 1024                   // threads per block (16 waves)

// Spatial binning: 42x42 cells of h=0.25 over [-5.25, 5.25).
// Drop terms with exp2(arg) < 2^-TCUT <=> sq > TCUT/cmag (r_cut^2).
// ell=0.1 -> cmag=72.13 -> r_cut=0.527 -> K=3, disc-shaped row windows.
// Planner falls back to full scans if ell too large for the grid.
#define NC 42
#define NCELLS (NC * NC)          // 1764
#define NPAIR (NCELLS / 2)        // 882
#define H 0.25f
#define INV_H 4.0f
#define ORIG (-5.25f)
#define TCUT 20.0f
#define KMAX 7
#define MAXROWS 16
#define NTW (M_PTS / 64)          // 256 test waves (M = 256*64, no padding)
#define CHUNK 1024
#define MAX_ITEMS 4096            // NTW * ceil(N/CHUNK) upper bound

// ws byte offsets (region [0, ZERO_BYTES) is hipMemsetAsync'd to 0 each call)
#define OFF_BAR 0                 // 4 ints: grid-barrier counters
#define OFF_NITEMS 32             // 1 int
#define OFF_HTR 64                // NCELLS ints
#define OFF_HTE (OFF_HTR + NCELLS * 4)
#define ZERO_BYTES (OFF_HTE + NCELLS * 4)      // 14176
#define OFF_TRCUR ZERO_BYTES
#define OFF_TECUR (OFF_TRCUR + NCELLS * 4)
#define OFF_SROW (OFF_TECUR + NCELLS * 4)      // int[NTW*MAXROWS]
#define OFF_SPRE (OFF_SROW + NTW * MAXROWS * 4)  // int[NTW*(MAXROWS+1)]
#define OFF_ITEMS (OFF_SPRE + NTW * (MAXROWS + 1) * 4)
#define OFF_TRA ((OFF_ITEMS + MAX_ITEMS * 4 + 255) & ~255)
#define OFF_TRW1 (OFF_TRA + N_PTS * 16)
#define OFF_T4 (OFF_TRW1 + N_PTS * 4)
#define WS_NEED (OFF_T4 + (size_t)M_PTS * 16)  // ~670 KB

__device__ __forceinline__ float fexp2(float x) {
#if __has_builtin(__builtin_amdgcn_exp2f)
    return __builtin_amdgcn_exp2f(x);
#else
    return exp2f(x);
#endif
}

__device__ __forceinline__ void gatomic_fadd(float* p, float v) {
    asm volatile("global_atomic_add_f32 %0, %1, off" :: "v"(p), "v"(v) : "memory");
}

__device__ __forceinline__ int cellco(float v) {
    int c = (int)floorf((v - ORIG) * INV_H);
    return min(NC - 1, max(0, c));
}

// Grid barrier: all NB blocks are co-resident by construction (LDS 47KB,
// VGPR<=128 => 2-block capacity per CU, grid == CU count). __threadfence()
// is an agent-scope fence (L2 writeback+invalidate across XCDs).
__device__ __forceinline__ void gbar(int* bar, int idx) {
    __syncthreads();
    if (threadIdx.x == 0) {
        __threadfence();
        atomicAdd(&bar[idx], 1);
        while (__hip_atomic_load(&bar[idx], __ATOMIC_RELAXED,
                                 __HIP_MEMORY_SCOPE_AGENT) < NB)
            __builtin_amdgcn_s_sleep(2);
        __threadfence();
    }
    __syncthreads();
}

__global__ __launch_bounds__(NT) void gp_fused(
        const float2* __restrict__ Xte, const float2* __restrict__ Xtr,
        const float2* __restrict__ alpha, const float* __restrict__ log_ell,
        const float* __restrict__ log_sf,
        int* bar, int* nitemsG, int* hTr, int* hTe,
        int* trcur, int* tecur, int* sRowG, int* sPreG, int* items,
        float4* trA, float* trW1, float4* T4, float* out) {
    __shared__ int sc[1024];
    __shared__ int trsL[NCELLS + 1];
    __shared__ int PL[NCELLS + 1];
    __shared__ float4 sA[CHUNK];                      // 16 KB
    __shared__ __align__(16) float sW[CHUNK];         // 4 KB
    __shared__ float2 red[16][64];                    // 8 KB
    __shared__ int off[MAXROWS];
    __shared__ int pre[MAXROWS + 1];

    const int tid = threadIdx.x;
    const int bid = blockIdx.x;

    // ---- P1: histogram (64 points per block, all CUs engaged) ----
    if (tid < 64) {
        int i = bid * 64 + tid;
        float2 t = Xtr[i];
        atomicAdd(&hTr[cellco(t.y) * NC + cellco(t.x)], 1);
        float2 x = Xte[i];
        atomicAdd(&hTe[cellco(x.y) * NC + cellco(x.x)], 1);
    }
    gbar(bar, 0);

    // ---- P2: block 0 scans + per-wave window planning ----
    if (bid == 0) {
        // pairwise scan of train counts (1764 = 2*882 <= 1024 pairs)
        int v = (tid < NPAIR) ? (hTr[2 * tid] + hTr[2 * tid + 1]) : 0;
        sc[tid] = v; __syncthreads();
        for (int o = 1; o < 1024; o <<= 1) {
            int u = (tid >= o) ? sc[tid - o] : 0;
            __syncthreads(); sc[tid] += u; __syncthreads();
        }
        if (tid < NPAIR) {
            int e = sc[tid] - v;
            trsL[2 * tid] = e;
            trsL[2 * tid + 1] = e + hTr[2 * tid];
        }
        if (tid == NPAIR - 1) trsL[NCELLS] = sc[tid];
        __syncthreads();
        // pairwise scan of test counts
        v = (tid < NPAIR) ? (hTe[2 * tid] + hTe[2 * tid + 1]) : 0;
        sc[tid] = v; __syncthreads();
        for (int o = 1; o < 1024; o <<= 1) {
            int u = (tid >= o) ? sc[tid - o] : 0;
            __syncthreads(); sc[tid] += u; __syncthreads();
        }
        if (tid < NPAIR) {
            int e = sc[tid] - v;
            PL[2 * tid] = e;
            PL[2 * tid + 1] = e + hTe[2 * tid];
        }
        if (tid == NPAIR - 1) PL[NCELLS] = sc[tid];
        __syncthreads();

        for (int c = tid; c < NCELLS; c += NT) {
            trcur[c] = trsL[c];
            tecur[c] = PL[c];
        }

        // planner: one thread per test wave of 64 consecutive sorted points
        if (tid < NTW) {
            const int w = tid;
            const float ell = expf(log_ell[0]);
            const float cmag = 0.5f / (ell * ell) * 1.4426950408889634f;
            const float r2 = TCUT / cmag;
            const int K = (int)floorf(sqrtf(r2) * INV_H) + 1;

            int clo, chi;
            {
                int s = w * 64, lo = 0, hi = NCELLS;
                while (lo + 1 < hi) { int m = (lo + hi) >> 1; if (PL[m] <= s) lo = m; else hi = m; }
                clo = lo;
                s = w * 64 + 63; lo = 0; hi = NCELLS;
                while (lo + 1 < hi) { int m = (lo + hi) >> 1; if (PL[m] <= s) lo = m; else hi = m; }
                chi = lo;
            }
            const int rl = clo / NC, cl = clo % NC;
            const int rh = chi / NC, ch = chi % NC;
            int wlo = max(0, rl - K), whi = min(NC - 1, rh + K);
            int nr = whi - wlo + 1;
            bool full = (K > KMAX) || (nr > MAXROWS);

            int preAcc = 0;
            if (full) {
                sRowG[w * MAXROWS] = 0;
                sPreG[w * (MAXROWS + 1)] = 0;
                preAcc = N_PTS;
                for (int i = 1; i <= MAXROWS; ++i)
                    sPreG[w * (MAXROWS + 1) + i] = N_PTS;
            } else {
                const bool single = (rl == rh);
                const int cmin = single ? cl : 0;
                const int cmax = single ? ch : (NC - 1);
                sPreG[w * (MAXROWS + 1)] = 0;
                int idx = 0;
                for (int wr = wlo; wr <= whi; ++wr, ++idx) {
                    int dy = (wr < rl) ? (rl - wr) : ((wr > rh) ? (wr - rh) : 0);
                    int kx;
                    if (dy <= 1) kx = K;
                    else {
                        float d = (float)(dy - 1) * H;
                        kx = (int)floorf(sqrtf(fmaxf(r2 - d * d, 0.f)) * INV_H) + 1;
                    }
                    int c0 = max(0, cmin - kx);
                    int c1 = min(NC - 1, cmax + kx);
                    int js = trsL[wr * NC + c0];
                    int je = trsL[wr * NC + c1 + 1];
                    sRowG[w * MAXROWS + idx] = js - preAcc;
                    preAcc += je - js;
                    sPreG[w * (MAXROWS + 1) + idx + 1] = preAcc;
                }
                for (; idx < MAXROWS; ++idx)
                    sPreG[w * (MAXROWS + 1) + idx + 1] = preAcc;
            }
            const int nch = (preAcc + CHUNK - 1) / CHUNK;
            int slot = atomicAdd(nitemsG, nch);
            for (int k = 0; k < nch; ++k)
                items[slot + k] = w | (k << 16);
        }
    }
    gbar(bar, 1);

    // ---- P3: scatter sorted/staged data + zero out ----
    if (tid < 64) {
        int i = bid * 64 + tid;
        ((float2*)out)[i] = make_float2(0.f, 0.f);
        float ell = expf(log_ell[0]);
        float sf2 = expf(2.0f * log_sf[0]);
        float c = -0.5f / (ell * ell) * 1.4426950408889634f;  // c < 0

        float2 t = Xtr[i];
        float2 a = alpha[i];
        int ct = cellco(t.y) * NC + cellco(t.x);
        int pt = atomicAdd(&trcur[ct], 1);
        trA[pt] = make_float4(-2.f * c * t.x, -2.f * c * t.y,
                              c * (t.x * t.x + t.y * t.y), sf2 * a.x);
        trW1[pt] = sf2 * a.y;

        float2 x = Xte[i];
        int cx = cellco(x.y) * NC + cellco(x.x);
        int px = atomicAdd(&tecur[cx], 1);
        T4[px] = make_float4(x.x, x.y, c * (x.x * x.x + x.y * x.y),
                             __int_as_float(i));
    }
    gbar(bar, 2);

    // ---- P4: item loop. Item = (test-wave w, CHUNK chunk k of its window).
    // 16 waves of the block all hold the same 64 test points; stage chunk to
    // LDS (1 train/thread), split 256 quads over 16 waves, branch-free exp2
    // (dummy pad slots underflow to 0), LDS-reduce, atomic add to out.
    const int nit = nitemsG[0];
    const int p = tid >> 6;
    const int lane = tid & 63;
    for (int it = bid; it < nit; it += NB) {
        const int item = items[it];
        const int w = item & 0xFFFF;
        const int k = item >> 16;
        if (tid < MAXROWS) off[tid] = sRowG[w * MAXROWS + tid];
        if (tid < MAXROWS + 1) pre[tid] = sPreG[w * (MAXROWS + 1) + tid];
        float4 tp = T4[w * 64 + lane];
        __syncthreads();

        const int total = pre[MAXROWS];
        const int base0 = k << 10;
        const int n = min(CHUNK, total - base0);
        {
            float4 tv; float wv;
            if (tid < n) {
                int gg = base0 + tid;
                int r = 0;
                while (gg >= pre[r + 1]) ++r;     // <= MAXROWS steps
                int j = gg + off[r];
                tv = trA[j];
                wv = trW1[j];
            } else {
                tv = make_float4(0.f, 0.f, -1.0e30f, 0.f);
                wv = 0.f;
            }
            sA[tid] = tv;
            sW[tid] = wv;
        }
        __syncthreads();

        const float x = tp.x, y = tp.y, b = tp.z;
        const int oi = __float_as_int(tp.w);
        float a0 = 0.f, a1 = 0.f;
#pragma unroll 2
        for (int q = p; q < CHUNK / 4; q += 16) {
            float4 t0 = sA[4 * q];
            float4 t1 = sA[4 * q + 1];
            float4 t2 = sA[4 * q + 2];
            float4 t3 = sA[4 * q + 3];
            float4 wv = *(const float4*)&sW[4 * q];
            float e0 = fexp2(fmaf(t0.x, x, fmaf(t0.y, y, b + t0.z)));
            float e1 = fexp2(fmaf(t1.x, x, fmaf(t1.y, y, b + t1.z)));
            float e2 = fexp2(fmaf(t2.x, x, fmaf(t2.y, y, b + t2.z)));
            float e3 = fexp2(fmaf(t3.x, x, fmaf(t3.y, y, b + t3.z)));
            a0 = fmaf(e0, t0.w, a0); a1 = fmaf(e0, wv.x, a1);
            a0 = fmaf(e1, t1.w, a0); a1 = fmaf(e1, wv.y, a1);
            a0 = fmaf(e2, t2.w, a0); a1 = fmaf(e2, wv.z, a1);
            a0 = fmaf(e3, t3.w, a0); a1 = fmaf(e3, wv.w, a1);
        }
        red[p][lane] = make_float2(a0, a1);
        __syncthreads();
        if (p == 0) {
            float s0 = 0.f, s1 = 0.f;
#pragma unroll
            for (int q = 0; q < 16; ++q) {
                float2 vq = red[q][lane];
                s0 += vq.x; s1 += vq.y;
            }
            if (s0 != 0.f || s1 != 0.f) {
                gatomic_fadd(&out[2 * oi], s0);
                gatomic_fadd(&out[2 * oi + 1], s1);
            }
        }
        __syncthreads();   // red/sA reuse by next item
    }
}

// --- dense fallback (ws too small) ------------------------------------------
__global__ __launch_bounds__(256, 8) void gp_dense(
        const float2* __restrict__ Xte, const float2* __restrict__ Xtr,
        const float2* __restrict__ alpha, const float* __restrict__ log_ell,
        const float* __restrict__ log_sf, float* __restrict__ out) {
    __shared__ float4 sSt[128];
    __shared__ float sA1[128];
    const int tid = threadIdx.x;
    const float ell = expf(log_ell[0]);
    const float c = -0.5f / (ell * ell) * 1.4426950408889634f;
    const int j0 = blockIdx.y * 128;
    if (tid < 128) {
        const float sf2 = expf(2.0f * log_sf[0]);
        float2 t = Xtr[j0 + tid];
        float2 a = alpha[j0 + tid];
        sSt[tid] = make_float4(-2.f * c * t.x, -2.f * c * t.y,
                               c * (t.x * t.x + t.y * t.y), sf2 * a.x);
        sA1[tid] = sf2 * a.y;
    }
    const int base = blockIdx.x * 1024 + tid;
    float2 x0 = Xte[base], x1 = Xte[base + 256];
    float2 x2 = Xte[base + 512], x3 = Xte[base + 768];
    const float b0 = c * (x0.x * x0.x + x0.y * x0.y);
    const float b1 = c * (x1.x * x1.x + x1.y * x1.y);
    const float b2 = c * (x2.x * x2.x + x2.y * x2.y);
    const float b3 = c * (x3.x * x3.x + x3.y * x3.y);
    __syncthreads();
    float a00 = 0.f, a01 = 0.f, a10 = 0.f, a11 = 0.f;
    float a20 = 0.f, a21 = 0.f, a30 = 0.f, a31 = 0.f;
#pragma unroll 2
    for (int j = 0; j < 128; ++j) {
        float4 s = sSt[j];
        float w1 = sA1[j];
        float e0 = fexp2(fminf(fmaf(s.x, x0.x, fmaf(s.y, x0.y, b0 + s.z)), 0.f));
        float e1 = fexp2(fminf(fmaf(s.x, x1.x, fmaf(s.y, x1.y, b1 + s.z)), 0.f));
        float e2 = fexp2(fminf(fmaf(s.x, x2.x, fmaf(s.y, x2.y, b2 + s.z)), 0.f));
        float e3 = fexp2(fminf(fmaf(s.x, x3.x, fmaf(s.y, x3.y, b3 + s.z)), 0.f));
        a00 = fmaf(e0, s.w, a00); a01 = fmaf(e0, w1, a01);
        a10 = fmaf(e1, s.w, a10); a11 = fmaf(e1, w1, a11);
        a20 = fmaf(e2, s.w, a20); a21 = fmaf(e2, w1, a21);
        a30 = fmaf(e3, s.w, a30); a31 = fmaf(e3, w1, a31);
    }
    gatomic_fadd(&out[2 * base], a00);            gatomic_fadd(&out[2 * base + 1], a01);
    gatomic_fadd(&out[2 * (base + 256)], a10);    gatomic_fadd(&out[2 * (base + 256) + 1], a11);
    gatomic_fadd(&out[2 * (base + 512)], a20);    gatomic_fadd(&out[2 * (base + 512) + 1], a21);
    gatomic_fadd(&out[2 * (base + 768)], a30);    gatomic_fadd(&out[2 * (base + 768) + 1], a31);
}

extern "C" void kernel_launch(void* const* d_in, const int* in_sizes, int n_in,
                              void* d_out, int out_size, void* d_ws, size_t ws_size,
                              hipStream_t stream) {
    const float2* Xte = (const float2*)d_in[0];
    const float2* Xtr = (const float2*)d_in[1];
    const float2* alpha = (const float2*)d_in[2];
    const float* log_ell = (const float*)d_in[3];
    const float* log_sf = (const float*)d_in[4];
    float* out = (float*)d_out;

    if (ws_size >= WS_NEED) {
        char* ws = (char*)d_ws;
        int* bar = (int*)(ws + OFF_BAR);
        int* nitems = (int*)(ws + OFF_NITEMS);
        int* hTr = (int*)(ws + OFF_HTR);
        int* hTe = (int*)(ws + OFF_HTE);
        int* trcur = (int*)(ws + OFF_TRCUR);
        int* tecur = (int*)(ws + OFF_TECUR);
        int* sRowG = (int*)(ws + OFF_SROW);
        int* sPreG = (int*)(ws + OFF_SPRE);
        int* items = (int*)(ws + OFF_ITEMS);
        float4* trA = (float4*)(ws + OFF_TRA);
        float* trW1 = (float*)(ws + OFF_TRW1);
        float4* T4 = (float4*)(ws + OFF_T4);

        hipMemsetAsync(ws, 0, ZERO_BYTES, stream);   // bar + nitems + hists
        gp_fused<<<NB, NT, 0, stream>>>(Xte, Xtr, alpha, log_ell, log_sf,
                                        bar, nitems, hTr, hTe, trcur, tecur,
                                        sRowG, sPreG, items, trA, trW1, T4, out);
    } else {
        hipMemsetAsync(out, 0, (size_t)out_size * sizeof(float), stream);
        dim3 grid(M_PTS / 1024, N_PTS / 128);
        gp_dense<<<grid, 256, 0, stream>>>(Xte, Xtr, alpha, log_ell, log_sf, out);
    }
}

// Round 8
// 146.242 us; speedup vs baseline: 1.0650x; 1.0650x over previous
//
#include <hip/hip_runtime.h>
#include <math.h>

// Problem constants (fixed by the reference).
#define M_PTS 16384
#define N_PTS 16384

// Spatial binning: 42x42 cells of h=0.25 over [-5.25, 5.25).
// Drop terms with exp2(arg) < 2^-TCUT <=> sq > TCUT/cmag (r_cut^2).
// ell=0.1 -> cmag=72.13 -> r_cut=0.527 -> K=3, disc-shaped row windows.
// Planner falls back to full scans if ell too large for the grid.
#define NC 42
#define NCELLS (NC * NC)          // 1764
#define NPAIR (NCELLS / 2)        // 882
#define H 0.25f
#define INV_H 4.0f
#define ORIG (-5.25f)
#define TCUT 20.0f
#define KMAX 7
#define MAXROWS 16
#define NTW (M_PTS / 64)          // 256 test waves (M = 256*64, no padding)
#define CHUNK 1024
#define MAXCH 16                  // max chunks per wave (full scan = 16)

// ws byte offsets ([0, 2*NCELLS*4) is hipMemsetAsync'd to 0 each call)
#define OFF_HTR 0                 // NCELLS ints
#define OFF_HTE (OFF_HTR + NCELLS * 4)
#define OFF_TRCUR (OFF_HTE + NCELLS * 4)
#define OFF_TECUR (OFF_TRCUR + NCELLS * 4)
#define OFF_SROW (OFF_TECUR + NCELLS * 4)        // int[NTW*MAXROWS]
#define OFF_SPRE (OFF_SROW + NTW * MAXROWS * 4)  // int[NTW*(MAXROWS+1)]
#define OFF_TRA ((OFF_SPRE + NTW * (MAXROWS + 1) * 4 + 255) & ~255)
#define OFF_TRW1 (OFF_TRA + N_PTS * 16)
#define OFF_T4 (OFF_TRW1 + N_PTS * 4)
#define WS_NEED (OFF_T4 + (size_t)M_PTS * 16)    // ~660 KB

__device__ __forceinline__ float fexp2(float x) {
#if __has_builtin(__builtin_amdgcn_exp2f)
    return __builtin_amdgcn_exp2f(x);
#else
    return exp2f(x);
#endif
}

__device__ __forceinline__ void gatomic_fadd(float* p, float v) {
    asm volatile("global_atomic_add_f32 %0, %1, off" :: "v"(p), "v"(v) : "memory");
}

__device__ __forceinline__ int cellco(float v) {
    int c = (int)floorf((v - ORIG) * INV_H);
    return min(NC - 1, max(0, c));
}

// --- dA: multi-block histogram + zero out ------------------------------------
__global__ __launch_bounds__(256) void hist_kernel(
        const float2* __restrict__ Xtr, const float2* __restrict__ Xte,
        int* __restrict__ hTr, int* __restrict__ hTe,
        float2* __restrict__ out2) {
    int i = blockIdx.x * 256 + threadIdx.x;
    out2[i] = make_float2(0.f, 0.f);
    float2 t = Xtr[i];
    atomicAdd(&hTr[cellco(t.y) * NC + cellco(t.x)], 1);
    float2 x = Xte[i];
    atomicAdd(&hTe[cellco(x.y) * NC + cellco(x.x)], 1);
}

// --- dB: scans + per-wave window planning, one thin block --------------------
__global__ __launch_bounds__(1024) void scan_plan_kernel(
        const int* __restrict__ hTr, const int* __restrict__ hTe,
        const float* __restrict__ log_ell,
        int* __restrict__ trcur, int* __restrict__ tecur,
        int* __restrict__ sRowG, int* __restrict__ sPreG) {
    __shared__ int sc[1024];
    __shared__ int trsL[NCELLS + 1];
    __shared__ int PL[NCELLS + 1];
    const int tid = threadIdx.x;

    // pairwise scan of train counts (1764 = 2*882)
    int hv0 = (tid < NPAIR) ? hTr[2 * tid] : 0;
    int hv1 = (tid < NPAIR) ? hTr[2 * tid + 1] : 0;
    int v = hv0 + hv1;
    sc[tid] = v; __syncthreads();
    for (int o = 1; o < 1024; o <<= 1) {
        int u = (tid >= o) ? sc[tid - o] : 0;
        __syncthreads(); sc[tid] += u; __syncthreads();
    }
    if (tid < NPAIR) {
        int e = sc[tid] - v;
        trsL[2 * tid] = e;
        trsL[2 * tid + 1] = e + hv0;
    }
    if (tid == NPAIR - 1) trsL[NCELLS] = sc[tid];
    __syncthreads();
    // pairwise scan of test counts
    hv0 = (tid < NPAIR) ? hTe[2 * tid] : 0;
    hv1 = (tid < NPAIR) ? hTe[2 * tid + 1] : 0;
    v = hv0 + hv1;
    sc[tid] = v; __syncthreads();
    for (int o = 1; o < 1024; o <<= 1) {
        int u = (tid >= o) ? sc[tid - o] : 0;
        __syncthreads(); sc[tid] += u; __syncthreads();
    }
    if (tid < NPAIR) {
        int e = sc[tid] - v;
        PL[2 * tid] = e;
        PL[2 * tid + 1] = e + hv0;
    }
    if (tid == NPAIR - 1) PL[NCELLS] = sc[tid];
    __syncthreads();

    for (int c = tid; c < NCELLS; c += 1024) {
        trcur[c] = trsL[c];
        tecur[c] = PL[c];
    }

    // planner: one thread per test wave of 64 consecutive sorted points
    if (tid < NTW) {
        const int w = tid;
        const float ell = expf(log_ell[0]);
        const float cmag = 0.5f / (ell * ell) * 1.4426950408889634f;
        const float r2 = TCUT / cmag;
        const int K = (int)floorf(sqrtf(r2) * INV_H) + 1;

        int clo, chi;
        {
            int s = w * 64, lo = 0, hi = NCELLS;
            while (lo + 1 < hi) { int m = (lo + hi) >> 1; if (PL[m] <= s) lo = m; else hi = m; }
            clo = lo;
            s = w * 64 + 63; lo = 0; hi = NCELLS;
            while (lo + 1 < hi) { int m = (lo + hi) >> 1; if (PL[m] <= s) lo = m; else hi = m; }
            chi = lo;
        }
        const int rl = clo / NC, cl = clo % NC;
        const int rh = chi / NC, ch = chi % NC;
        int wlo = max(0, rl - K), whi = min(NC - 1, rh + K);
        int nr = whi - wlo + 1;
        bool full = (K > KMAX) || (nr > MAXROWS);

        int preAcc = 0;
        if (full) {
            sRowG[w * MAXROWS] = 0;
            sPreG[w * (MAXROWS + 1)] = 0;
            preAcc = N_PTS;
            for (int i = 1; i <= MAXROWS; ++i)
                sPreG[w * (MAXROWS + 1) + i] = N_PTS;
        } else {
            const bool single = (rl == rh);
            const int cmin = single ? cl : 0;
            const int cmax = single ? ch : (NC - 1);
            sPreG[w * (MAXROWS + 1)] = 0;
            int idx = 0;
            for (int wr = wlo; wr <= whi; ++wr, ++idx) {
                int dy = (wr < rl) ? (rl - wr) : ((wr > rh) ? (wr - rh) : 0);
                int kx;
                if (dy <= 1) kx = K;
                else {
                    float d = (float)(dy - 1) * H;
                    kx = (int)floorf(sqrtf(fmaxf(r2 - d * d, 0.f)) * INV_H) + 1;
                }
                int c0 = max(0, cmin - kx);
                int c1 = min(NC - 1, cmax + kx);
                int js = trsL[wr * NC + c0];
                int je = trsL[wr * NC + c1 + 1];
                sRowG[w * MAXROWS + idx] = js - preAcc;   // j = gg + offset
                preAcc += je - js;
                sPreG[w * (MAXROWS + 1) + idx + 1] = preAcc;
            }
            for (; idx < MAXROWS; ++idx)
                sPreG[w * (MAXROWS + 1) + idx + 1] = preAcc;
        }
    }
}

// --- dC: scatter sorted/staged data -----------------------------------------
// trA[p] = (-2c*t0, -2c*t1, c*|t|^2, sf2*a0), trW1[p] = sf2*a1.
// T4[p] = (x, y, c*|x|^2, orig idx bits).
__global__ __launch_bounds__(256) void scatter_kernel(
        const float2* __restrict__ Xtr, const float2* __restrict__ Xte,
        const float2* __restrict__ alpha, const float* __restrict__ log_ell,
        const float* __restrict__ log_sf,
        int* __restrict__ trcur, int* __restrict__ tecur,
        float4* __restrict__ trA, float* __restrict__ trW1,
        float4* __restrict__ T4) {
    int i = blockIdx.x * 256 + threadIdx.x;
    float ell = expf(log_ell[0]);
    float sf2 = expf(2.0f * log_sf[0]);
    float c = -0.5f / (ell * ell) * 1.4426950408889634f;  // * log2(e), c < 0

    float2 t = Xtr[i];
    float2 a = alpha[i];
    int ct = cellco(t.y) * NC + cellco(t.x);
    int pt = atomicAdd(&trcur[ct], 1);
    trA[pt] = make_float4(-2.f * c * t.x, -2.f * c * t.y,
                          c * (t.x * t.x + t.y * t.y), sf2 * a.x);
    trW1[pt] = sf2 * a.y;

    float2 x = Xte[i];
    int cx = cellco(x.y) * NC + cellco(x.x);
    int px = atomicAdd(&tecur[cx], 1);
    T4[px] = make_float4(x.x, x.y, c * (x.x * x.x + x.y * x.y),
                         __int_as_float(i));
}

// --- dD: main kernel ---------------------------------------------------------
// Static grid (chunk k, test-wave w). Block = 256 threads = 4 waves holding
// the same 64 test points; stage the chunk to LDS (coalesced via per-row
// offset table), 4 waves split the quads, branch-free exp2 (pad slots
// underflow to 0), LDS-reduce, atomicAdd 2 floats per lane. Blocks whose
// chunk lies beyond the wave's window exit immediately.
__global__ __launch_bounds__(256) void gp_main(
        const float4* __restrict__ T4, const float4* __restrict__ trA,
        const float* __restrict__ trW1, const int* __restrict__ sRowG,
        const int* __restrict__ sPreG, float* __restrict__ out) {
    const int w = blockIdx.y;
    const int k = blockIdx.x;

    __shared__ float4 sA[CHUNK];                     // 16 KB
    __shared__ __align__(16) float sW[CHUNK];        // 4 KB
    __shared__ float2 red[4][64];                    // 2 KB
    __shared__ int off[MAXROWS];
    __shared__ int pre[MAXROWS + 1];

    const int tid = threadIdx.x;
    const int p = tid >> 6;          // wave 0..3
    const int lane = tid & 63;

    if (tid < MAXROWS) off[tid] = sRowG[w * MAXROWS + tid];
    if (tid < MAXROWS + 1) pre[tid] = sPreG[w * (MAXROWS + 1) + tid];
    __syncthreads();

    const int total = pre[MAXROWS];
    const int base0 = k << 10;
    if (base0 >= total) return;

    float4 tp = T4[w * 64 + lane];
    const int n = min(CHUNK, total - base0);

    // stage (row-search per thread; <= MAXROWS steps, gg monotone per thread)
    {
        float4 tv; float wv;
        if (tid < n) {
            int gg = base0 + tid;
            int r = 0;
            while (gg >= pre[r + 1]) ++r;
            int j = gg + off[r];
            tv = trA[j];
            wv = trW1[j];
        } else {
            tv = make_float4(0.f, 0.f, -1.0e30f, 0.f);
            wv = 0.f;
        }
        sA[tid] = tv;
        sW[tid] = wv;
        // second 512 slots
        int g2 = tid + 256;
        if (g2 < CHUNK) {
            if (g2 < n) {
                int gg = base0 + g2;
                int r = 0;
                while (gg >= pre[r + 1]) ++r;
                int j = gg + off[r];
                tv = trA[j];
                wv = trW1[j];
            } else {
                tv = make_float4(0.f, 0.f, -1.0e30f, 0.f);
                wv = 0.f;
            }
            sA[g2] = tv;
            sW[g2] = wv;
        }
        for (int g = tid + 512; g < CHUNK; g += 256) {
            if (g < n) {
                int gg = base0 + g;
                int r = 0;
                while (gg >= pre[r + 1]) ++r;
                int j = gg + off[r];
                tv = trA[j];
                wv = trW1[j];
            } else {
                tv = make_float4(0.f, 0.f, -1.0e30f, 0.f);
                wv = 0.f;
            }
            sA[g] = tv;
            sW[g] = wv;
        }
    }
    __syncthreads();

    const float x = tp.x, y = tp.y, b = tp.z;
    const int oi = __float_as_int(tp.w);
    float a0 = 0.f, a1 = 0.f;
#pragma unroll 2
    for (int q = p; q < CHUNK / 4; q += 4) {
        float4 t0 = sA[4 * q];
        float4 t1 = sA[4 * q + 1];
        float4 t2 = sA[4 * q + 2];
        float4 t3 = sA[4 * q + 3];
        float4 wv = *(const float4*)&sW[4 * q];
        float e0 = fexp2(fmaf(t0.x, x, fmaf(t0.y, y, b + t0.z)));
        float e1 = fexp2(fmaf(t1.x, x, fmaf(t1.y, y, b + t1.z)));
        float e2 = fexp2(fmaf(t2.x, x, fmaf(t2.y, y, b + t2.z)));
        float e3 = fexp2(fmaf(t3.x, x, fmaf(t3.y, y, b + t3.z)));
        a0 = fmaf(e0, t0.w, a0); a1 = fmaf(e0, wv.x, a1);
        a0 = fmaf(e1, t1.w, a0); a1 = fmaf(e1, wv.y, a1);
        a0 = fmaf(e2, t2.w, a0); a1 = fmaf(e2, wv.z, a1);
        a0 = fmaf(e3, t3.w, a0); a1 = fmaf(e3, wv.w, a1);
    }

    red[p][lane] = make_float2(a0, a1);
    __syncthreads();
    if (p == 0) {
        float s0 = 0.f, s1 = 0.f;
#pragma unroll
        for (int q = 0; q < 4; ++q) {
            float2 vq = red[q][lane];
            s0 += vq.x; s1 += vq.y;
        }
        if (s0 != 0.f || s1 != 0.f) {
            gatomic_fadd(&out[2 * oi], s0);
            gatomic_fadd(&out[2 * oi + 1], s1);
        }
    }
}

// --- dense fallback (ws too small) ------------------------------------------
__global__ __launch_bounds__(256, 8) void gp_dense(
        const float2* __restrict__ Xte, const float2* __restrict__ Xtr,
        const float2* __restrict__ alpha, const float* __restrict__ log_ell,
        const float* __restrict__ log_sf, float* __restrict__ out) {
    __shared__ float4 sSt[128];
    __shared__ float sA1[128];
    const int tid = threadIdx.x;
    const float ell = expf(log_ell[0]);
    const float c = -0.5f / (ell * ell) * 1.4426950408889634f;
    const int j0 = blockIdx.y * 128;
    if (tid < 128) {
        const float sf2 = expf(2.0f * log_sf[0]);
        float2 t = Xtr[j0 + tid];
        float2 a = alpha[j0 + tid];
        sSt[tid] = make_float4(-2.f * c * t.x, -2.f * c * t.y,
                               c * (t.x * t.x + t.y * t.y), sf2 * a.x);
        sA1[tid] = sf2 * a.y;
    }
    const int base = blockIdx.x * 1024 + tid;
    float2 x0 = Xte[base], x1 = Xte[base + 256];
    float2 x2 = Xte[base + 512], x3 = Xte[base + 768];
    const float b0 = c * (x0.x * x0.x + x0.y * x0.y);
    const float b1 = c * (x1.x * x1.x + x1.y * x1.y);
    const float b2 = c * (x2.x * x2.x + x2.y * x2.y);
    const float b3 = c * (x3.x * x3.x + x3.y * x3.y);
    __syncthreads();
    float a00 = 0.f, a01 = 0.f, a10 = 0.f, a11 = 0.f;
    float a20 = 0.f, a21 = 0.f, a30 = 0.f, a31 = 0.f;
#pragma unroll 2
    for (int j = 0; j < 128; ++j) {
        float4 s = sSt[j];
        float w1 = sA1[j];
        float e0 = fexp2(fminf(fmaf(s.x, x0.x, fmaf(s.y, x0.y, b0 + s.z)), 0.f));
        float e1 = fexp2(fminf(fmaf(s.x, x1.x, fmaf(s.y, x1.y, b1 + s.z)), 0.f));
        float e2 = fexp2(fminf(fmaf(s.x, x2.x, fmaf(s.y, x2.y, b2 + s.z)), 0.f));
        float e3 = fexp2(fminf(fmaf(s.x, x3.x, fmaf(s.y, x3.y, b3 + s.z)), 0.f));
        a00 = fmaf(e0, s.w, a00); a01 = fmaf(e0, w1, a01);
        a10 = fmaf(e1, s.w, a10); a11 = fmaf(e1, w1, a11);
        a20 = fmaf(e2, s.w, a20); a21 = fmaf(e2, w1, a21);
        a30 = fmaf(e3, s.w, a30); a31 = fmaf(e3, w1, a31);
    }
    gatomic_fadd(&out[2 * base], a00);            gatomic_fadd(&out[2 * base + 1], a01);
    gatomic_fadd(&out[2 * (base + 256)], a10);    gatomic_fadd(&out[2 * (base + 256) + 1], a11);
    gatomic_fadd(&out[2 * (base + 512)], a20);    gatomic_fadd(&out[2 * (base + 512) + 1], a21);
    gatomic_fadd(&out[2 * (base + 768)], a30);    gatomic_fadd(&out[2 * (base + 768) + 1], a31);
}

extern "C" void kernel_launch(void* const* d_in, const int* in_sizes, int n_in,
                              void* d_out, int out_size, void* d_ws, size_t ws_size,
                              hipStream_t stream) {
    const float2* Xte = (const float2*)d_in[0];
    const float2* Xtr = (const float2*)d_in[1];
    const float2* alpha = (const float2*)d_in[2];
    const float* log_ell = (const float*)d_in[3];
    const float* log_sf = (const float*)d_in[4];
    float* out = (float*)d_out;

    if (ws_size >= WS_NEED) {
        char* ws = (char*)d_ws;
        int* hTr = (int*)(ws + OFF_HTR);
        int* hTe = (int*)(ws + OFF_HTE);
        int* trcur = (int*)(ws + OFF_TRCUR);
        int* tecur = (int*)(ws + OFF_TECUR);
        int* sRowG = (int*)(ws + OFF_SROW);
        int* sPreG = (int*)(ws + OFF_SPRE);
        float4* trA = (float4*)(ws + OFF_TRA);
        float* trW1 = (float*)(ws + OFF_TRW1);
        float4* T4 = (float4*)(ws + OFF_T4);

        hipMemsetAsync(hTr, 0, 2 * NCELLS * sizeof(int), stream);
        hist_kernel<<<M_PTS / 256, 256, 0, stream>>>(Xtr, Xte, hTr, hTe,
                                                     (float2*)out);
        scan_plan_kernel<<<1, 1024, 0, stream>>>(hTr, hTe, log_ell,
                                                 trcur, tecur, sRowG, sPreG);
        scatter_kernel<<<N_PTS / 256, 256, 0, stream>>>(
            Xtr, Xte, alpha, log_ell, log_sf, trcur, tecur, trA, trW1, T4);
        dim3 grid(MAXCH, NTW);
        gp_main<<<grid, 256, 0, stream>>>(T4, trA, trW1, sRowG, sPreG, out);
    } else {
        hipMemsetAsync(out, 0, (size_t)out_size * sizeof(float), stream);
        dim3 grid(M_PTS / 1024, N_PTS / 128);
        gp_dense<<<grid, 256, 0, stream>>>(Xte, Xtr, alpha, log_ell, log_sf, out);
    }
}

// Round 9
// 118.826 us; speedup vs baseline: 1.3107x; 1.2307x over previous
//
#include <hip/hip_runtime.h>
#include <math.h>

// Problem constants (fixed by the reference).
#define M_PTS 16384
#define N_PTS 16384

// Spatial binning: 42x42 cells of h=0.25 over [-5.25, 5.25).
// Drop terms with exp2(arg) < 2^-TCUT <=> sq > TCUT/cmag (r_cut^2).
// ell=0.1 -> cmag=72.13 -> r_cut=0.527 -> K=3, per-point disc windows.
// K > 31 (huge ell) -> single full-scan span (still correct).
#define NC 42
#define NCELLS (NC * NC)          // 1764
#define NPAIR (NCELLS / 2)        // 882
#define H 0.25f
#define INV_H 4.0f
#define ORIG (-5.25f)
#define TCUT 20.0f
#define KCAP 31                   // lane-parallel span fetch needs 2K+1 <= 63

// ws byte offsets ([OFF_HTR, +NCELLS*4) is hipMemsetAsync'd to 0 each call)
#define OFF_HTR 0                 // NCELLS ints (histogram)
#define OFF_TRS (OFF_HTR + NCELLS * 4)        // (NCELLS+1) ints, row starts
#define OFF_TRCUR (OFF_TRS + (NCELLS + 1) * 4 + 60)  // NCELLS ints
#define OFF_TRA ((OFF_TRCUR + NCELLS * 4 + 255) & ~255)  // float4[N]
#define OFF_TRW1 (OFF_TRA + N_PTS * 16)
#define WS_NEED (OFF_TRW1 + (size_t)N_PTS * 4)  // ~350 KB

__device__ __forceinline__ float fexp2(float x) {
#if __has_builtin(__builtin_amdgcn_exp2f)
    return __builtin_amdgcn_exp2f(x);
#else
    return exp2f(x);
#endif
}

__device__ __forceinline__ void gatomic_fadd(float* p, float v) {
    asm volatile("global_atomic_add_f32 %0, %1, off" :: "v"(p), "v"(v) : "memory");
}

__device__ __forceinline__ int cellco(float v) {
    int c = (int)floorf((v - ORIG) * INV_H);
    return min(NC - 1, max(0, c));
}

// --- dA: train histogram -----------------------------------------------------
__global__ __launch_bounds__(256) void hist_kernel(
        const float2* __restrict__ Xtr, int* __restrict__ hTr) {
    int i = blockIdx.x * 256 + threadIdx.x;
    float2 t = Xtr[i];
    atomicAdd(&hTr[cellco(t.y) * NC + cellco(t.x)], 1);
}

// --- dB: prefix scan of train counts (one thin block) ------------------------
__global__ __launch_bounds__(1024) void scan_kernel(
        const int* __restrict__ hTr, int* __restrict__ trs,
        int* __restrict__ trcur) {
    __shared__ int sc[1024];
    const int tid = threadIdx.x;
    int hv0 = (tid < NPAIR) ? hTr[2 * tid] : 0;
    int hv1 = (tid < NPAIR) ? hTr[2 * tid + 1] : 0;
    int v = hv0 + hv1;
    sc[tid] = v; __syncthreads();
    for (int o = 1; o < 1024; o <<= 1) {
        int u = (tid >= o) ? sc[tid - o] : 0;
        __syncthreads(); sc[tid] += u; __syncthreads();
    }
    if (tid < NPAIR) {
        int e = sc[tid] - v;
        trs[2 * tid] = e;      trcur[2 * tid] = e;
        trs[2 * tid + 1] = e + hv0;  trcur[2 * tid + 1] = e + hv0;
    }
    if (tid == NPAIR - 1) trs[NCELLS] = sc[tid];
}

// --- dC: scatter staged train data into cell-sorted order --------------------
// trA[p] = (-2c*t0, -2c*t1, c*|t|^2, sf2*a0), trW1[p] = sf2*a1;
// c = -0.5/ell^2 * log2(e), so K = sf2 * exp2(arg), arg = c*sq <= 0.
__global__ __launch_bounds__(256) void scatter_kernel(
        const float2* __restrict__ Xtr, const float2* __restrict__ alpha,
        const float* __restrict__ log_ell, const float* __restrict__ log_sf,
        int* __restrict__ trcur, float4* __restrict__ trA,
        float* __restrict__ trW1) {
    int i = blockIdx.x * 256 + threadIdx.x;
    float ell = expf(log_ell[0]);
    float sf2 = expf(2.0f * log_sf[0]);
    float c = -0.5f / (ell * ell) * 1.4426950408889634f;

    float2 t = Xtr[i];
    float2 a = alpha[i];
    int ct = cellco(t.y) * NC + cellco(t.x);
    int pt = atomicAdd(&trcur[ct], 1);
    trA[pt] = make_float4(-2.f * c * t.x, -2.f * c * t.y,
                          c * (t.x * t.x + t.y * t.y), sf2 * a.x);
    trW1[pt] = sf2 * a.y;
}

// --- dD: main kernel — one wave per test point -------------------------------
// 64 lanes scan 64 trains/iter of this point's disc window with per-lane
// coalesced global_load_dwordx4 (no LDS, no syncthreads, no atomics).
// Row spans are fetched lane-parallel once, then broadcast via __shfl.
// 16384 waves -> full occupancy; branch-free inner body (cndmask + exp2).
__global__ __launch_bounds__(256) void gp_point(
        const float2* __restrict__ Xte, const float4* __restrict__ trA,
        const float* __restrict__ trW1, const int* __restrict__ trs,
        const float* __restrict__ log_ell, float2* __restrict__ out2) {
    const int wid = (blockIdx.x << 2) + (threadIdx.x >> 6);  // 0..M_PTS-1
    const int lane = threadIdx.x & 63;

    const float ell = expf(log_ell[0]);
    const float cmag = 0.5f / (ell * ell) * 1.4426950408889634f;
    const float r2 = TCUT / cmag;

    const float2 xt = Xte[wid];
    const float b = -cmag * (xt.x * xt.x + xt.y * xt.y);  // c*|x|^2

    int K = (int)floorf(sqrtf(r2) * INV_H) + 1;
    int js_l = 0, je_l = 0;
    int nrows;
    if (K > KCAP) {
        nrows = 1;
        if (lane == 0) { js_l = 0; je_l = N_PTS; }   // full scan (correct always)
    } else {
        nrows = 2 * K + 1;
        const int cx = cellco(xt.x), cy = cellco(xt.y);
        if (lane < nrows) {
            int ry = cy - K + lane;
            if (ry >= 0 && ry < NC) {
                int dy = (lane < K) ? (K - lane) : (lane - K);
                int kx;
                if (dy <= 1) kx = K;
                else {
                    float d = (float)(dy - 1) * H;
                    kx = (int)floorf(sqrtf(fmaxf(r2 - d * d, 0.f)) * INV_H) + 1;
                }
                int c0 = max(0, cx - kx);
                int c1 = min(NC - 1, cx + kx);
                js_l = trs[ry * NC + c0];     // per-lane (divergent) loads
                je_l = trs[ry * NC + c1 + 1];
            }
        }
    }

    float a0 = 0.f, a1 = 0.f;
    for (int rr = 0; rr < nrows; ++rr) {
        const int js = __shfl(js_l, rr);
        const int je = __shfl(je_l, rr);
        for (int j0 = js; j0 < je; j0 += 64) {
            int j = j0 + lane;
            int jc = min(j, je - 1);          // in-range clamp (je >= 1 here)
            float4 tv = trA[jc];              // coalesced 16B/lane
            float w1 = trW1[jc];
            float arg = fmaf(tv.x, xt.x, fmaf(tv.y, xt.y, b + tv.z));
            arg = (j < je) ? arg : -1.0e30f;  // mask clamped duplicates
            float e = fexp2(arg);             // underflows to 0 when far
            a0 = fmaf(e, tv.w, a0);
            a1 = fmaf(e, w1, a1);
        }
    }

    // 64-lane butterfly reduction
    for (int o = 32; o > 0; o >>= 1) {
        a0 += __shfl_xor(a0, o);
        a1 += __shfl_xor(a1, o);
    }
    if (lane == 0) out2[wid] = make_float2(a0, a1);  // sole owner: plain store
}

// --- dense fallback (ws too small) ------------------------------------------
__global__ __launch_bounds__(256, 8) void gp_dense(
        const float2* __restrict__ Xte, const float2* __restrict__ Xtr,
        const float2* __restrict__ alpha, const float* __restrict__ log_ell,
        const float* __restrict__ log_sf, float* __restrict__ out) {
    __shared__ float4 sSt[128];
    __shared__ float sA1[128];
    const int tid = threadIdx.x;
    const float ell = expf(log_ell[0]);
    const float c = -0.5f / (ell * ell) * 1.4426950408889634f;
    const int j0 = blockIdx.y * 128;
    if (tid < 128) {
        const float sf2 = expf(2.0f * log_sf[0]);
        float2 t = Xtr[j0 + tid];
        float2 a = alpha[j0 + tid];
        sSt[tid] = make_float4(-2.f * c * t.x, -2.f * c * t.y,
                               c * (t.x * t.x + t.y * t.y), sf2 * a.x);
        sA1[tid] = sf2 * a.y;
    }
    const int base = blockIdx.x * 1024 + tid;
    float2 x0 = Xte[base], x1 = Xte[base + 256];
    float2 x2 = Xte[base + 512], x3 = Xte[base + 768];
    const float b0 = c * (x0.x * x0.x + x0.y * x0.y);
    const float b1 = c * (x1.x * x1.x + x1.y * x1.y);
    const float b2 = c * (x2.x * x2.x + x2.y * x2.y);
    const float b3 = c * (x3.x * x3.x + x3.y * x3.y);
    __syncthreads();
    float a00 = 0.f, a01 = 0.f, a10 = 0.f, a11 = 0.f;
    float a20 = 0.f, a21 = 0.f, a30 = 0.f, a31 = 0.f;
#pragma unroll 2
    for (int j = 0; j < 128; ++j) {
        float4 s = sSt[j];
        float w1 = sA1[j];
        float e0 = fexp2(fminf(fmaf(s.x, x0.x, fmaf(s.y, x0.y, b0 + s.z)), 0.f));
        float e1 = fexp2(fminf(fmaf(s.x, x1.x, fmaf(s.y, x1.y, b1 + s.z)), 0.f));
        float e2 = fexp2(fminf(fmaf(s.x, x2.x, fmaf(s.y, x2.y, b2 + s.z)), 0.f));
        float e3 = fexp2(fminf(fmaf(s.x, x3.x, fmaf(s.y, x3.y, b3 + s.z)), 0.f));
        a00 = fmaf(e0, s.w, a00); a01 = fmaf(e0, w1, a01);
        a10 = fmaf(e1, s.w, a10); a11 = fmaf(e1, w1, a11);
        a20 = fmaf(e2, s.w, a20); a21 = fmaf(e2, w1, a21);
        a30 = fmaf(e3, s.w, a30); a31 = fmaf(e3, w1, a31);
    }
    gatomic_fadd(&out[2 * base], a00);            gatomic_fadd(&out[2 * base + 1], a01);
    gatomic_fadd(&out[2 * (base + 256)], a10);    gatomic_fadd(&out[2 * (base + 256) + 1], a11);
    gatomic_fadd(&out[2 * (base + 512)], a20);    gatomic_fadd(&out[2 * (base + 512) + 1], a21);
    gatomic_fadd(&out[2 * (base + 768)], a30);    gatomic_fadd(&out[2 * (base + 768) + 1], a31);
}

extern "C" void kernel_launch(void* const* d_in, const int* in_sizes, int n_in,
                              void* d_out, int out_size, void* d_ws, size_t ws_size,
                              hipStream_t stream) {
    const float2* Xte = (const float2*)d_in[0];
    const float2* Xtr = (const float2*)d_in[1];
    const float2* alpha = (const float2*)d_in[2];
    const float* log_ell = (const float*)d_in[3];
    const float* log_sf = (const float*)d_in[4];
    float* out = (float*)d_out;

    if (ws_size >= WS_NEED) {
        char* ws = (char*)d_ws;
        int* hTr = (int*)(ws + OFF_HTR);
        int* trs = (int*)(ws + OFF_TRS);
        int* trcur = (int*)(ws + OFF_TRCUR);
        float4* trA = (float4*)(ws + OFF_TRA);
        float* trW1 = (float*)(ws + OFF_TRW1);

        hipMemsetAsync(hTr, 0, NCELLS * sizeof(int), stream);
        hist_kernel<<<N_PTS / 256, 256, 0, stream>>>(Xtr, hTr);
        scan_kernel<<<1, 1024, 0, stream>>>(hTr, trs, trcur);
        scatter_kernel<<<N_PTS / 256, 256, 0, stream>>>(Xtr, alpha, log_ell,
                                                        log_sf, trcur, trA, trW1);
        gp_point<<<M_PTS / 4, 256, 0, stream>>>(Xte, trA, trW1, trs, log_ell,
                                                (float2*)out);
    } else {
        hipMemsetAsync(out, 0, (size_t)out_size * sizeof(float), stream);
        dim3 grid(M_PTS / 1024, N_PTS / 128);
        gp_dense<<<grid, 256, 0, stream>>>(Xte, Xtr, alpha, log_ell, log_sf, out);
    }
}